// Round 10
// baseline (186.298 us; speedup 1.0000x reference)
//
#include <hip/hip_runtime.h>
#include <hip/hip_fp16.h>

// Batched quantum-circuit sim. ONE launch, 1-D grid, 256-thread blocks,
// two UNIFORM block roles (R9 structure, fastest so far):
//  - blocks [0, gx):     ABC: one thread per element, sims A+B+C,
//                        writes out[b*9+0..5]
//  - blocks [gx, gx+gy): 7q sim, FOUR lanes/element (qubits 0,1 = lane
//                        bits), 32 amps/lane in an SSA vector (vreg32).
// R9 counters: residency pinned at 2 waves/SIMD (VGPR 80 burns a 128-reg
// HW slot); VALUBusy 70% = 30% latency stalls. 4-lane split (math verified
// in R5) + SSA state -> ~57 live regs; __launch_bounds__(256,8) pins the
// allocator at the 64-VGPR/8-wave step. 2-4x residency, no spill expected.

#define DEVINL __device__ __forceinline__

typedef _Float16 hv2 __attribute__((ext_vector_type(2)));
typedef unsigned int u32;
typedef u32 vreg16 __attribute__((ext_vector_type(16)));
typedef u32 vreg32 __attribute__((ext_vector_type(32)));

struct C2 { __half2 rr, mp; };  // complex const (r,i): rr=(r,r), mp=(-i,+i)

DEVINL C2 mkc(float re, float im) {
  C2 c; c.rr = __floats2half2_rn(re, re); c.mp = __floats2half2_rn(-im, im); return c;
}
DEVINL __half2 mkamp(float re, float im) { return __floats2half2_rn(re, im); }
DEVINL __half2 swap2(__half2 v) { return __lowhigh2highlow(v); }
// (const u) * (amp v):  (r*vr - i*vi, r*vi + i*vr)
DEVINL __half2 cmulc(C2 u, __half2 v) { return __hfma2(u.rr, v, __hmul2(u.mp, swap2(v))); }

DEVINL float ampsq(__half2 v, float acc) {
#if __has_builtin(__builtin_amdgcn_fdot2)
  return __builtin_amdgcn_fdot2(__builtin_bit_cast(hv2, v), __builtin_bit_cast(hv2, v), acc, false);
#else
  float2 f = __half22float2(v);
  return fmaf(f.x, f.x, fmaf(f.y, f.y, acc));
#endif
}

constexpr int parc(int x) { x ^= x >> 4; x ^= x >> 2; x ^= x >> 1; return x & 1; }

struct c32 { float x, y; };
DEVINL c32 cmulf(c32 a, c32 b) { return { a.x*b.x - a.y*b.y, a.x*b.y + a.y*b.x }; }

// ---- SSA state accessors (constant-index extract/insert) -------------------
template<class VT>
DEVINL __half2 vget(const VT& A, int i) { return __builtin_bit_cast(__half2, (u32)A[i]); }
template<class VT>
DEVINL void vset(VT& A, int i, __half2 v) { A[i] = __builtin_bit_cast(u32, v); }

// ---- lane^K exchange via shfl_xor (verified path, R3/R5) -------------------
template<int K>
DEVINL __half2 lxk(__half2 v) {
  int q = __shfl_xor(__builtin_bit_cast(int, v), K, 64);
  return __builtin_bit_cast(__half2, q);
}
template<int K>
DEVINL float lxkf(float v) { return __shfl_xor(v, K, 64); }

// ---------------- generic gates (qubit W of N; mask = 1<<(N-1-W)) -----------

template<int N, int W, class VT>
DEVINL void g_ry(VT& A, __half2 c2, __half2 s2, __half2 ns2) {
  constexpr int M = 1 << (N - 1 - W);
#pragma unroll
  for (int i = 0; i < (1 << N); ++i) if (!(i & M)) {
    const int j = i | M;
    __half2 v0 = vget(A, i), v1 = vget(A, j);
    vset(A, i, __hfma2(c2, v0, __hmul2(ns2, v1)));
    vset(A, j, __hfma2(c2, v1, __hmul2(s2, v0)));
  }
}

template<int N, int W, class VT>
DEVINL void g_u2(VT& A, C2 u00, C2 u01, C2 u10, C2 u11) {
  constexpr int M = 1 << (N - 1 - W);
#pragma unroll
  for (int i = 0; i < (1 << N); ++i) if (!(i & M)) {
    const int j = i | M;
    __half2 v0 = vget(A, i), v1 = vget(A, j), v0s = swap2(v0), v1s = swap2(v1);
    vset(A, i, __hfma2(u00.rr, v0, __hfma2(u00.mp, v0s, __hfma2(u01.rr, v1, __hmul2(u01.mp, v1s)))));
    vset(A, j, __hfma2(u10.rr, v0, __hfma2(u10.mp, v0s, __hfma2(u11.rr, v1, __hmul2(u11.mp, v1s)))));
  }
}

template<int N, int C, int T, class VT>
DEVINL void g_cnot(VT& A) {
  constexpr int CM = 1 << (N - 1 - C), TM = 1 << (N - 1 - T);
#pragma unroll
  for (int i = 0; i < (1 << N); ++i) if ((i & CM) && !(i & TM)) {
    const int j = i | TM;
    __half2 t = vget(A, i); vset(A, i, vget(A, j)); vset(A, j, t);
  }
}

template<int N, int K, class VT>
DEVINL void chain_cnot(VT& A) {
  if constexpr (K < N - 1) { g_cnot<N, K, K + 1>(A); chain_cnot<N, K + 1>(A); }
}

// ---------------- per-qubit coefficients (f32) ------------------------------
// forward: u = Rz(phi)Ry(pt)Rx(eta)|0>;  reverse merged: U = Rx(phi)Ry(pt)Rz(eta)

DEVINL void mk_u01(float ce, float se, float cp, float sp, float cf, float sf,
                   c32& u0, c32& u1) {
  u0 = cmulf({cf, -sf}, {cp * ce, sp * se});
  u1 = cmulf({cf,  sf}, {sp * ce, -cp * se});
}

DEVINL void mk_U(float ce, float se, float cp, float sp, float cf, float sf,
                 C2& U00, C2& U01, C2& U10, C2& U11) {
  c32 z = {ce, -se}, zb = {ce, se};
  c32 A = cmulf({cf * cp, -sf * sp}, z);
  c32 T = cmulf({cf * sp,  sf * cp}, zb);
  c32 Cc = cmulf({cf * sp, -sf * cp}, z);
  c32 D = cmulf({cf * cp,  sf * sp}, zb);
  U00 = mkc(A.x, A.y); U01 = mkc(-T.x, -T.y); U10 = mkc(Cc.x, Cc.y); U11 = mkc(D.x, D.y);
}

// per-qubit sincos loader (eta_i<0 -> eta=0)
DEVINL void load_sc(const float* __restrict__ xr, int eta_i, int pt_i, int phi_i,
                    float& ce, float& se, float& cp, float& sp, float& cf, float& sf) {
  float e = (eta_i < 0) ? 0.f : xr[eta_i];
  __sincosf(0.5f * e, &se, &ce);
  __sincosf(0.5f * xr[pt_i], &sp, &cp);
  __sincosf(0.5f * xr[phi_i], &sf, &cf);
}

// product state build by doubling (A[0] must be (1,0) on entry).
// step M's qubit lands at bit (N-1-M). CF(M,u0,u1) supplies the column.
template<int N, int M, class VT, class CF>
DEVINL void build_rec(VT& A, CF cf) {
  if constexpr (M < N) {
    c32 u0, u1; cf(M, u0, u1);
    C2 c0 = mkc(u0.x, u0.y), c1 = mkc(u1.x, u1.y);
#pragma unroll
    for (int j = (1 << M) - 1; j >= 0; --j) {
      __half2 s = vget(A, j);
      vset(A, 2 * j,     cmulc(c0, s));
      vset(A, 2 * j + 1, cmulc(c1, s));
    }
    build_rec<N, M + 1>(A, cf);
  }
}

template<int N, int K, class VT, class CF>
DEVINL void usweep_rec(VT& A, CF cf) {
  if constexpr (K < N) {
    C2 U00, U01, U10, U11;
    cf(K, U00, U01, U10, U11);
    g_u2<N, K>(A, U00, U01, U10, U11);
    usweep_rec<N, K + 1>(A, cf);
  }
}

template<int N, int K, class VT, class CF>
DEVINL void ry_rec(VT& A, CF cf) {
  if constexpr (K < N) {
    __half2 c2, s2, ns2;
    cf(K, c2, s2, ns2);
    g_ry<N, K>(A, c2, s2, ns2);
    ry_rec<N, K + 1>(A, cf);
  }
}

// ---------------- 4-qubit block I (verified math, SSA state) ----------------

template<int I>
DEVINL void sim4h(const float* __restrict__ xr, const float* __restrict__ w, float* z) {
  constexpr int PT[3][4]  = {{5, 4, 35, 34}, {3, 33, 31, 2}, {28, 32, 15, 16}};
  constexpr int ETA[3][4] = {{9, 8, 45, 44}, {7, 43, 41, 6}, {38, 42, 19, 20}};
  constexpr int PHI[3][4] = {{13, 12, 55, 54}, {11, 53, 51, 10}, {48, 52, 23, 24}};
  vreg16 A;
  vset(A, 0, mkamp(1.f, 0.f));
  build_rec<4, 0>(A, [&](int M, c32& u0, c32& u1) {
    float ce, se, cp, sp, cf, sf;
    load_sc(xr, ETA[I][M], PT[I][M], PHI[I][M], ce, se, cp, sp, cf, sf);
    mk_u01(ce, se, cp, sp, cf, sf, u0, u1);
  });
  chain_cnot<4, 0>(A);
  usweep_rec<4, 0>(A, [&](int K, C2& U00, C2& U01, C2& U10, C2& U11) {
    float ce, se, cp, sp, cf, sf;
    load_sc(xr, ETA[I][K], PT[I][K], PHI[I][K], ce, se, cp, sp, cf, sf);
    mk_U(ce, se, cp, sp, cf, sf, U00, U01, U10, U11);
  });

  // t->l CNOT block == flip q0,q1 (mask 12) iff parity(b2,b3) (i&3)
#pragma unroll
  for (int i = 0; i < 16; ++i)
    if (parc(i & 3) && !(i & 8)) {
      __half2 t = vget(A, i); vset(A, i, vget(A, i ^ 12)); vset(A, i ^ 12, t);
    }

  ry_rec<4, 0>(A, [&](int K, __half2& c2, __half2& s2, __half2& ns2) {
    float sv, cv; __sincosf(0.5f * w[K], &sv, &cv);
    c2 = __floats2half2_rn(cv, cv);
    s2 = __floats2half2_rn(sv, sv);
    ns2 = __floats2half2_rn(-sv, -sv);
  });

  // l->t CNOT block == flip q2,q3 (mask 3) iff parity(b0,b1) (i&12)
#pragma unroll
  for (int i = 0; i < 16; ++i)
    if (parc(i & 12) && !(i & 2)) {
      __half2 t = vget(A, i); vset(A, i, vget(A, i ^ 3)); vset(A, i ^ 3, t);
    }

  float cls[4];
#pragma unroll
  for (int c = 0; c < 4; ++c) cls[c] = 0.f;
#pragma unroll
  for (int i = 0; i < 16; ++i) cls[i & 3] = ampsq(vget(A, i), cls[i & 3]);
  float z0 = 0.f, z1 = 0.f;
#pragma unroll
  for (int c = 0; c < 4; ++c) {
    z0 += (c & 2) ? -cls[c] : cls[c];
    z1 += (c & 1) ? -cls[c] : cls[c];
  }
  z[0] = z0; z[1] = z1;
}

// ---------------- 7q body, 4 lanes/element (R5-verified math, SSA state) ----
// sub = t&3 = (q0<<1)|q1. Local index i (5 bits): qubit k>=2 at bit 6-k
// (q2=16, q3=8, q4=4, q5=2, q6=1). q0 partner = lane^2, q1 partner = lane^1.

DEVINL void role7(const float* __restrict__ xr, const float* __restrict__ wD,
                  float* __restrict__ out_row, int sub) {
  const bool b0 = (sub & 2) != 0;     // qubit 0 value
  const bool b1 = (sub & 1) != 0;     // qubit 1 value

  constexpr int PT[7]  = {0, 14, 30, 26, 29, 27, 17};
  constexpr int ETA[7] = {-1, 18, 40, 36, 39, 37, 21};  // -1 -> zeros (None)
  constexpr int PHI[7] = {1, 22, 50, 46, 49, 47, 25};

  vreg32 A;
  vset(A, 0, mkamp(1.f, 0.f));
  // build qubits 2..6 locally: step M = qubit M+2 -> local bit 4-M = 6-(M+2)
  build_rec<5, 0>(A, [&](int M, c32& u0, c32& u1) {
    const int k = M + 2;
    float ce, se, cp, sp, cf, sf;
    load_sc(xr, ETA[k], PT[k], PHI[k], ce, se, cp, sp, cf, sf);
    mk_u01(ce, se, cp, sp, cf, sf, u0, u1);
  });
  { // combined q0,q1 product factor selected by lane bits
    float ce, se, cp, sp, cf, sf;
    load_sc(xr, ETA[0], PT[0], PHI[0], ce, se, cp, sp, cf, sf);
    c32 q0u0, q0u1; mk_u01(ce, se, cp, sp, cf, sf, q0u0, q0u1);
    load_sc(xr, ETA[1], PT[1], PHI[1], ce, se, cp, sp, cf, sf);
    c32 q1u0, q1u1; mk_u01(ce, se, cp, sp, cf, sf, q1u0, q1u1);
    c32 f0 = b0 ? q0u1 : q0u0;
    c32 f1 = b1 ? q1u1 : q1u0;
    c32 f = cmulf(f0, f1);
    C2 cf2 = mkc(f.x, f.y);
#pragma unroll
    for (int i = 0; i < 32; ++i) vset(A, i, cmulc(cf2, vget(A, i)));
  }

  // CNOT(0,1): lanes with q0=1 exchange with partner over q1 (lane^1)
#pragma unroll
  for (int i = 0; i < 32; ++i) {
    __half2 q = lxk<1>(vget(A, i));
    if (true) vset(A, i, b0 ? q : vget(A, i));
  }
  // CNOT(1,2): lanes with q1=1 flip local bit4 (q2)
#pragma unroll
  for (int i = 0; i < 16; ++i) {
    const int j = i | 16;
    __half2 lo = vget(A, i), hi = vget(A, j);
    vset(A, i, b1 ? hi : lo);
    vset(A, j, b1 ? lo : hi);
  }
  // CNOT(2,3)..(5,6): local chain (renames)
  chain_cnot<5, 0>(A);

  // merged-U sweep: q0 (lane^2), q1 (lane^1), then q2..q6 local
  {
    float ce, se, cp, sp, cf, sf;
    load_sc(xr, ETA[0], PT[0], PHI[0], ce, se, cp, sp, cf, sf);
    C2 U00, U01, U10, U11;
    mk_U(ce, se, cp, sp, cf, sf, U00, U01, U10, U11);
    C2 UA, UB;  // out = UA*mine + UB*partner
    UA.rr = b0 ? U11.rr : U00.rr; UA.mp = b0 ? U11.mp : U00.mp;
    UB.rr = b0 ? U10.rr : U01.rr; UB.mp = b0 ? U10.mp : U01.mp;
#pragma unroll
    for (int i = 0; i < 32; ++i) {
      __half2 m = vget(A, i), q = lxk<2>(m);
      vset(A, i, __hfma2(UA.rr, m, __hfma2(UA.mp, swap2(m),
                 __hfma2(UB.rr, q, __hmul2(UB.mp, swap2(q))))));
    }
  }
  {
    float ce, se, cp, sp, cf, sf;
    load_sc(xr, ETA[1], PT[1], PHI[1], ce, se, cp, sp, cf, sf);
    C2 U00, U01, U10, U11;
    mk_U(ce, se, cp, sp, cf, sf, U00, U01, U10, U11);
    C2 UA, UB;
    UA.rr = b1 ? U11.rr : U00.rr; UA.mp = b1 ? U11.mp : U00.mp;
    UB.rr = b1 ? U10.rr : U01.rr; UB.mp = b1 ? U10.mp : U01.mp;
#pragma unroll
    for (int i = 0; i < 32; ++i) {
      __half2 m = vget(A, i), q = lxk<1>(m);
      vset(A, i, __hfma2(UA.rr, m, __hfma2(UA.mp, swap2(m),
                 __hfma2(UB.rr, q, __hmul2(UB.mp, swap2(q))))));
    }
  }
  usweep_rec<5, 0>(A, [&](int W, C2& U00, C2& U01, C2& U10, C2& U11) {
    const int k = W + 2;
    float ce, se, cp, sp, cf, sf;
    load_sc(xr, ETA[k], PT[k], PHI[k], ce, se, cp, sp, cf, sf);
    mk_U(ce, se, cp, sp, cf, sf, U00, U01, U10, U11);
  });

  // depth loop kept rolled: body stays in L1I
#pragma unroll 1
  for (int d = 0; d < 4; ++d) {
    // P1 (t->l): flip q0..q3 iff parity(q4,q5,q6)=parc(i&7).
    // Pairs {(lane,i),(lane^3,i^0x18)}: a[i] <- old partner a[i^0x18]
#pragma unroll
    for (int i = 0; i < 32; ++i)
      if (parc(i & 7) && !(i & 0x10)) {
        const int j = i ^ 0x18;
        __half2 t0 = lxk<3>(vget(A, j));
        __half2 t1 = lxk<3>(vget(A, i));
        vset(A, i, t0); vset(A, j, t1);
      }

    // Ry q0 (lane^2): out = c*mine + (b0? s : -s)*partner
    {
      float sv, cv; __sincosf(0.5f * wD[7 * d], &sv, &cv);
      __half2 c2v = __floats2half2_rn(cv, cv);
      __half2 se2 = __floats2half2_rn(b0 ? sv : -sv, b0 ? sv : -sv);
#pragma unroll
      for (int i = 0; i < 32; ++i) {
        __half2 q = lxk<2>(vget(A, i));
        vset(A, i, __hfma2(c2v, vget(A, i), __hmul2(se2, q)));
      }
    }
    // Ry q1 (lane^1)
    {
      float sv, cv; __sincosf(0.5f * wD[7 * d + 1], &sv, &cv);
      __half2 c2v = __floats2half2_rn(cv, cv);
      __half2 se2 = __floats2half2_rn(b1 ? sv : -sv, b1 ? sv : -sv);
#pragma unroll
      for (int i = 0; i < 32; ++i) {
        __half2 q = lxk<1>(vget(A, i));
        vset(A, i, __hfma2(c2v, vget(A, i), __hmul2(se2, q)));
      }
    }
    // Ry q2..q6 local
    ry_rec<5, 0>(A, [&](int W, __half2& c2, __half2& s2, __half2& ns2) {
      float sv, cv; __sincosf(0.5f * wD[7 * d + W + 2], &sv, &cv);
      c2 = __floats2half2_rn(cv, cv);
      s2 = __floats2half2_rn(sv, sv);
      ns2 = __floats2half2_rn(-sv, -sv);
    });

    // P2 (l->t): flip q4..q6 (local ^7) iff parity(q0..q3) =
    // parc(sub) ^ parc(i&0x18)  (lane-local swap)
    {
      const bool ps = b0 ^ b1;
#pragma unroll
      for (int i = 0; i < 32; ++i)
        if (!(i & 4)) {          // rep of pair {i, i^7}
          const int j = i ^ 7;
          const bool cond = parc(i & 0x18) ? !ps : ps;
          __half2 lo = vget(A, i), hi = vget(A, j);
          vset(A, i, cond ? hi : lo);
          vset(A, j, cond ? lo : hi);
        }
    }
  }

  // readout: class c = q4q5q6 = i&7 (local); quad-sum cross-lane
  float cls[8];
#pragma unroll
  for (int c = 0; c < 8; ++c) cls[c] = 0.f;
#pragma unroll
  for (int i = 0; i < 32; ++i) cls[i & 7] = ampsq(vget(A, i), cls[i & 7]);
  float z4 = 0.f, z5 = 0.f, z6 = 0.f;
#pragma unroll
  for (int c = 0; c < 8; ++c) {
    z4 += (c & 4) ? -cls[c] : cls[c];
    z5 += (c & 2) ? -cls[c] : cls[c];
    z6 += (c & 1) ? -cls[c] : cls[c];
  }
  z4 += lxkf<1>(z4); z5 += lxkf<1>(z5); z6 += lxkf<1>(z6);
  z4 += lxkf<2>(z4); z5 += lxkf<2>(z5); z6 += lxkf<2>(z6);
  if (sub == 0) {
    out_row[6] = z4; out_row[7] = z5; out_row[8] = z6;
  }
}

// ---------------- single fused-dispatch kernel ------------------------------

__global__ void __launch_bounds__(256, 8)
k_all(const float* __restrict__ x,
      const float* __restrict__ wA, const float* __restrict__ wB,
      const float* __restrict__ wC, const float* __restrict__ wD,
      float* __restrict__ out, int B, int gx) {
  const int bx = blockIdx.x;
  if (bx < gx) {
    // ABC role: one thread per element, all three 4q sims
    const int b = bx * 256 + threadIdx.x;
    if (b >= B) return;
    const float* xr = x + (size_t)b * 56;
    float o[6];
    sim4h<0>(xr, wA, &o[0]);
    sim4h<1>(xr, wB, &o[2]);
    sim4h<2>(xr, wC, &o[4]);
    float* op = out + (size_t)b * 9;
#pragma unroll
    for (int i = 0; i < 6; ++i) op[i] = o[i];
  } else {
    // 7q role: 4 lanes per element
    const int t = (bx - gx) * 256 + threadIdx.x;
    const int b = t >> 2;
    if (b >= B) return;
    role7(x + (size_t)b * 56, wD, out + (size_t)b * 9, t & 3);
  }
}

// ---------------- launch ----------------------------------------------------

extern "C" void kernel_launch(void* const* d_in, const int* in_sizes, int n_in,
                              void* d_out, int out_size, void* d_ws, size_t ws_size,
                              hipStream_t stream) {
  const float* x  = (const float*)d_in[0];
  const float* wA = (const float*)d_in[1];
  const float* wB = (const float*)d_in[2];
  const float* wC = (const float*)d_in[3];
  const float* wD = (const float*)d_in[4];
  float* out = (float*)d_out;
  const int B = in_sizes[0] / 56;
  const int threads = 256;

  const int gx = (B + threads - 1) / threads;          // ABC blocks
  const int gy = (4 * B + threads - 1) / threads;      // 7q blocks (4 lanes/elem)
  k_all<<<gx + gy, threads, 0, stream>>>(x, wA, wB, wC, wD, out, B, gx);
}

// Round 11
// 157.003 us; speedup vs baseline: 1.1866x; 1.1866x over previous
//
#include <hip/hip_runtime.h>
#include <hip/hip_fp16.h>

// Batched quantum-circuit sim. ONE launch, 1-D grid, 256-thread blocks,
// two UNIFORM block roles:
//  - blocks [0, gx):     ABC: one thread per element, sims A+B+C,
//                        writes out[b*9+0..5]
//  - blocks [gx, gx+gy): 7q sim, FOUR lanes/element (qubits 0,1 = lane
//                        bits), 32 amps/lane in an SSA vector (vreg32).
// R10 (launch_bounds(256,8)) proved the 4-lane MATH correct but the 64-reg
// budget made the allocator spill the 32-reg state tuple wholesale
// (VGPR=32, 340MB scratch traffic). R11 changes ONE knob: (256,6) ->
// 85-reg budget; tuple(32)+temps(~25) fits without spill, and a <=64
// landing unlocks the 8-wave/SIMD residency step.

#define DEVINL __device__ __forceinline__

typedef _Float16 hv2 __attribute__((ext_vector_type(2)));
typedef unsigned int u32;
typedef u32 vreg16 __attribute__((ext_vector_type(16)));
typedef u32 vreg32 __attribute__((ext_vector_type(32)));

struct C2 { __half2 rr, mp; };  // complex const (r,i): rr=(r,r), mp=(-i,+i)

DEVINL C2 mkc(float re, float im) {
  C2 c; c.rr = __floats2half2_rn(re, re); c.mp = __floats2half2_rn(-im, im); return c;
}
DEVINL __half2 mkamp(float re, float im) { return __floats2half2_rn(re, im); }
DEVINL __half2 swap2(__half2 v) { return __lowhigh2highlow(v); }
// (const u) * (amp v):  (r*vr - i*vi, r*vi + i*vr)
DEVINL __half2 cmulc(C2 u, __half2 v) { return __hfma2(u.rr, v, __hmul2(u.mp, swap2(v))); }

DEVINL float ampsq(__half2 v, float acc) {
#if __has_builtin(__builtin_amdgcn_fdot2)
  return __builtin_amdgcn_fdot2(__builtin_bit_cast(hv2, v), __builtin_bit_cast(hv2, v), acc, false);
#else
  float2 f = __half22float2(v);
  return fmaf(f.x, f.x, fmaf(f.y, f.y, acc));
#endif
}

constexpr int parc(int x) { x ^= x >> 4; x ^= x >> 2; x ^= x >> 1; return x & 1; }

struct c32 { float x, y; };
DEVINL c32 cmulf(c32 a, c32 b) { return { a.x*b.x - a.y*b.y, a.x*b.y + a.y*b.x }; }

// ---- SSA state accessors (constant-index extract/insert) -------------------
template<class VT>
DEVINL __half2 vget(const VT& A, int i) { return __builtin_bit_cast(__half2, (u32)A[i]); }
template<class VT>
DEVINL void vset(VT& A, int i, __half2 v) { A[i] = __builtin_bit_cast(u32, v); }

// ---- lane^K exchange via shfl_xor (verified path, R3/R5/R10) ---------------
template<int K>
DEVINL __half2 lxk(__half2 v) {
  int q = __shfl_xor(__builtin_bit_cast(int, v), K, 64);
  return __builtin_bit_cast(__half2, q);
}
template<int K>
DEVINL float lxkf(float v) { return __shfl_xor(v, K, 64); }

// ---------------- generic gates (qubit W of N; mask = 1<<(N-1-W)) -----------

template<int N, int W, class VT>
DEVINL void g_ry(VT& A, __half2 c2, __half2 s2, __half2 ns2) {
  constexpr int M = 1 << (N - 1 - W);
#pragma unroll
  for (int i = 0; i < (1 << N); ++i) if (!(i & M)) {
    const int j = i | M;
    __half2 v0 = vget(A, i), v1 = vget(A, j);
    vset(A, i, __hfma2(c2, v0, __hmul2(ns2, v1)));
    vset(A, j, __hfma2(c2, v1, __hmul2(s2, v0)));
  }
}

template<int N, int W, class VT>
DEVINL void g_u2(VT& A, C2 u00, C2 u01, C2 u10, C2 u11) {
  constexpr int M = 1 << (N - 1 - W);
#pragma unroll
  for (int i = 0; i < (1 << N); ++i) if (!(i & M)) {
    const int j = i | M;
    __half2 v0 = vget(A, i), v1 = vget(A, j), v0s = swap2(v0), v1s = swap2(v1);
    vset(A, i, __hfma2(u00.rr, v0, __hfma2(u00.mp, v0s, __hfma2(u01.rr, v1, __hmul2(u01.mp, v1s)))));
    vset(A, j, __hfma2(u10.rr, v0, __hfma2(u10.mp, v0s, __hfma2(u11.rr, v1, __hmul2(u11.mp, v1s)))));
  }
}

template<int N, int C, int T, class VT>
DEVINL void g_cnot(VT& A) {
  constexpr int CM = 1 << (N - 1 - C), TM = 1 << (N - 1 - T);
#pragma unroll
  for (int i = 0; i < (1 << N); ++i) if ((i & CM) && !(i & TM)) {
    const int j = i | TM;
    __half2 t = vget(A, i); vset(A, i, vget(A, j)); vset(A, j, t);
  }
}

template<int N, int K, class VT>
DEVINL void chain_cnot(VT& A) {
  if constexpr (K < N - 1) { g_cnot<N, K, K + 1>(A); chain_cnot<N, K + 1>(A); }
}

// ---------------- per-qubit coefficients (f32) ------------------------------
// forward: u = Rz(phi)Ry(pt)Rx(eta)|0>;  reverse merged: U = Rx(phi)Ry(pt)Rz(eta)

DEVINL void mk_u01(float ce, float se, float cp, float sp, float cf, float sf,
                   c32& u0, c32& u1) {
  u0 = cmulf({cf, -sf}, {cp * ce, sp * se});
  u1 = cmulf({cf,  sf}, {sp * ce, -cp * se});
}

DEVINL void mk_U(float ce, float se, float cp, float sp, float cf, float sf,
                 C2& U00, C2& U01, C2& U10, C2& U11) {
  c32 z = {ce, -se}, zb = {ce, se};
  c32 A = cmulf({cf * cp, -sf * sp}, z);
  c32 T = cmulf({cf * sp,  sf * cp}, zb);
  c32 Cc = cmulf({cf * sp, -sf * cp}, z);
  c32 D = cmulf({cf * cp,  sf * sp}, zb);
  U00 = mkc(A.x, A.y); U01 = mkc(-T.x, -T.y); U10 = mkc(Cc.x, Cc.y); U11 = mkc(D.x, D.y);
}

// per-qubit sincos loader (eta_i<0 -> eta=0)
DEVINL void load_sc(const float* __restrict__ xr, int eta_i, int pt_i, int phi_i,
                    float& ce, float& se, float& cp, float& sp, float& cf, float& sf) {
  float e = (eta_i < 0) ? 0.f : xr[eta_i];
  __sincosf(0.5f * e, &se, &ce);
  __sincosf(0.5f * xr[pt_i], &sp, &cp);
  __sincosf(0.5f * xr[phi_i], &sf, &cf);
}

// product state build by doubling (A[0] must be (1,0) on entry).
// step M's qubit lands at bit (N-1-M). CF(M,u0,u1) supplies the column.
template<int N, int M, class VT, class CF>
DEVINL void build_rec(VT& A, CF cf) {
  if constexpr (M < N) {
    c32 u0, u1; cf(M, u0, u1);
    C2 c0 = mkc(u0.x, u0.y), c1 = mkc(u1.x, u1.y);
#pragma unroll
    for (int j = (1 << M) - 1; j >= 0; --j) {
      __half2 s = vget(A, j);
      vset(A, 2 * j,     cmulc(c0, s));
      vset(A, 2 * j + 1, cmulc(c1, s));
    }
    build_rec<N, M + 1>(A, cf);
  }
}

template<int N, int K, class VT, class CF>
DEVINL void usweep_rec(VT& A, CF cf) {
  if constexpr (K < N) {
    C2 U00, U01, U10, U11;
    cf(K, U00, U01, U10, U11);
    g_u2<N, K>(A, U00, U01, U10, U11);
    usweep_rec<N, K + 1>(A, cf);
  }
}

template<int N, int K, class VT, class CF>
DEVINL void ry_rec(VT& A, CF cf) {
  if constexpr (K < N) {
    __half2 c2, s2, ns2;
    cf(K, c2, s2, ns2);
    g_ry<N, K>(A, c2, s2, ns2);
    ry_rec<N, K + 1>(A, cf);
  }
}

// ---------------- 4-qubit block I (verified math, SSA state) ----------------

template<int I>
DEVINL void sim4h(const float* __restrict__ xr, const float* __restrict__ w, float* z) {
  constexpr int PT[3][4]  = {{5, 4, 35, 34}, {3, 33, 31, 2}, {28, 32, 15, 16}};
  constexpr int ETA[3][4] = {{9, 8, 45, 44}, {7, 43, 41, 6}, {38, 42, 19, 20}};
  constexpr int PHI[3][4] = {{13, 12, 55, 54}, {11, 53, 51, 10}, {48, 52, 23, 24}};
  vreg16 A;
  vset(A, 0, mkamp(1.f, 0.f));
  build_rec<4, 0>(A, [&](int M, c32& u0, c32& u1) {
    float ce, se, cp, sp, cf, sf;
    load_sc(xr, ETA[I][M], PT[I][M], PHI[I][M], ce, se, cp, sp, cf, sf);
    mk_u01(ce, se, cp, sp, cf, sf, u0, u1);
  });
  chain_cnot<4, 0>(A);
  usweep_rec<4, 0>(A, [&](int K, C2& U00, C2& U01, C2& U10, C2& U11) {
    float ce, se, cp, sp, cf, sf;
    load_sc(xr, ETA[I][K], PT[I][K], PHI[I][K], ce, se, cp, sp, cf, sf);
    mk_U(ce, se, cp, sp, cf, sf, U00, U01, U10, U11);
  });

  // t->l CNOT block == flip q0,q1 (mask 12) iff parity(b2,b3) (i&3)
#pragma unroll
  for (int i = 0; i < 16; ++i)
    if (parc(i & 3) && !(i & 8)) {
      __half2 t = vget(A, i); vset(A, i, vget(A, i ^ 12)); vset(A, i ^ 12, t);
    }

  ry_rec<4, 0>(A, [&](int K, __half2& c2, __half2& s2, __half2& ns2) {
    float sv, cv; __sincosf(0.5f * w[K], &sv, &cv);
    c2 = __floats2half2_rn(cv, cv);
    s2 = __floats2half2_rn(sv, sv);
    ns2 = __floats2half2_rn(-sv, -sv);
  });

  // l->t CNOT block == flip q2,q3 (mask 3) iff parity(b0,b1) (i&12)
#pragma unroll
  for (int i = 0; i < 16; ++i)
    if (parc(i & 12) && !(i & 2)) {
      __half2 t = vget(A, i); vset(A, i, vget(A, i ^ 3)); vset(A, i ^ 3, t);
    }

  float cls[4];
#pragma unroll
  for (int c = 0; c < 4; ++c) cls[c] = 0.f;
#pragma unroll
  for (int i = 0; i < 16; ++i) cls[i & 3] = ampsq(vget(A, i), cls[i & 3]);
  float z0 = 0.f, z1 = 0.f;
#pragma unroll
  for (int c = 0; c < 4; ++c) {
    z0 += (c & 2) ? -cls[c] : cls[c];
    z1 += (c & 1) ? -cls[c] : cls[c];
  }
  z[0] = z0; z[1] = z1;
}

// ---------------- 7q body, 4 lanes/element (R10-verified math) --------------
// sub = t&3 = (q0<<1)|q1. Local index i (5 bits): qubit k>=2 at bit 6-k
// (q2=16, q3=8, q4=4, q5=2, q6=1). q0 partner = lane^2, q1 partner = lane^1.

DEVINL void role7(const float* __restrict__ xr, const float* __restrict__ wD,
                  float* __restrict__ out_row, int sub) {
  const bool b0 = (sub & 2) != 0;     // qubit 0 value
  const bool b1 = (sub & 1) != 0;     // qubit 1 value

  constexpr int PT[7]  = {0, 14, 30, 26, 29, 27, 17};
  constexpr int ETA[7] = {-1, 18, 40, 36, 39, 37, 21};  // -1 -> zeros (None)
  constexpr int PHI[7] = {1, 22, 50, 46, 49, 47, 25};

  vreg32 A;
  vset(A, 0, mkamp(1.f, 0.f));
  // build qubits 2..6 locally: step M = qubit M+2 -> local bit 4-M = 6-(M+2)
  build_rec<5, 0>(A, [&](int M, c32& u0, c32& u1) {
    const int k = M + 2;
    float ce, se, cp, sp, cf, sf;
    load_sc(xr, ETA[k], PT[k], PHI[k], ce, se, cp, sp, cf, sf);
    mk_u01(ce, se, cp, sp, cf, sf, u0, u1);
  });
  { // combined q0,q1 product factor selected by lane bits
    float ce, se, cp, sp, cf, sf;
    load_sc(xr, ETA[0], PT[0], PHI[0], ce, se, cp, sp, cf, sf);
    c32 q0u0, q0u1; mk_u01(ce, se, cp, sp, cf, sf, q0u0, q0u1);
    load_sc(xr, ETA[1], PT[1], PHI[1], ce, se, cp, sp, cf, sf);
    c32 q1u0, q1u1; mk_u01(ce, se, cp, sp, cf, sf, q1u0, q1u1);
    c32 f0 = b0 ? q0u1 : q0u0;
    c32 f1 = b1 ? q1u1 : q1u0;
    c32 f = cmulf(f0, f1);
    C2 cf2 = mkc(f.x, f.y);
#pragma unroll
    for (int i = 0; i < 32; ++i) vset(A, i, cmulc(cf2, vget(A, i)));
  }

  // CNOT(0,1): lanes with q0=1 exchange with partner over q1 (lane^1)
#pragma unroll
  for (int i = 0; i < 32; ++i) {
    __half2 q = lxk<1>(vget(A, i));
    vset(A, i, b0 ? q : vget(A, i));
  }
  // CNOT(1,2): lanes with q1=1 flip local bit4 (q2)
#pragma unroll
  for (int i = 0; i < 16; ++i) {
    const int j = i | 16;
    __half2 lo = vget(A, i), hi = vget(A, j);
    vset(A, i, b1 ? hi : lo);
    vset(A, j, b1 ? lo : hi);
  }
  // CNOT(2,3)..(5,6): local chain (renames)
  chain_cnot<5, 0>(A);

  // merged-U sweep: q0 (lane^2), q1 (lane^1), then q2..q6 local
  {
    float ce, se, cp, sp, cf, sf;
    load_sc(xr, ETA[0], PT[0], PHI[0], ce, se, cp, sp, cf, sf);
    C2 U00, U01, U10, U11;
    mk_U(ce, se, cp, sp, cf, sf, U00, U01, U10, U11);
    C2 UA, UB;  // out = UA*mine + UB*partner
    UA.rr = b0 ? U11.rr : U00.rr; UA.mp = b0 ? U11.mp : U00.mp;
    UB.rr = b0 ? U10.rr : U01.rr; UB.mp = b0 ? U10.mp : U01.mp;
#pragma unroll
    for (int i = 0; i < 32; ++i) {
      __half2 m = vget(A, i), q = lxk<2>(m);
      vset(A, i, __hfma2(UA.rr, m, __hfma2(UA.mp, swap2(m),
                 __hfma2(UB.rr, q, __hmul2(UB.mp, swap2(q))))));
    }
  }
  {
    float ce, se, cp, sp, cf, sf;
    load_sc(xr, ETA[1], PT[1], PHI[1], ce, se, cp, sp, cf, sf);
    C2 U00, U01, U10, U11;
    mk_U(ce, se, cp, sp, cf, sf, U00, U01, U10, U11);
    C2 UA, UB;
    UA.rr = b1 ? U11.rr : U00.rr; UA.mp = b1 ? U11.mp : U00.mp;
    UB.rr = b1 ? U10.rr : U01.rr; UB.mp = b1 ? U10.mp : U01.mp;
#pragma unroll
    for (int i = 0; i < 32; ++i) {
      __half2 m = vget(A, i), q = lxk<1>(m);
      vset(A, i, __hfma2(UA.rr, m, __hfma2(UA.mp, swap2(m),
                 __hfma2(UB.rr, q, __hmul2(UB.mp, swap2(q))))));
    }
  }
  usweep_rec<5, 0>(A, [&](int W, C2& U00, C2& U01, C2& U10, C2& U11) {
    const int k = W + 2;
    float ce, se, cp, sp, cf, sf;
    load_sc(xr, ETA[k], PT[k], PHI[k], ce, se, cp, sp, cf, sf);
    mk_U(ce, se, cp, sp, cf, sf, U00, U01, U10, U11);
  });

  // depth loop kept rolled: body stays in L1I
#pragma unroll 1
  for (int d = 0; d < 4; ++d) {
    // P1 (t->l): flip q0..q3 iff parity(q4,q5,q6)=parc(i&7).
    // Pairs {(lane,i),(lane^3,i^0x18)}: a[i] <- old partner a[i^0x18]
#pragma unroll
    for (int i = 0; i < 32; ++i)
      if (parc(i & 7) && !(i & 0x10)) {
        const int j = i ^ 0x18;
        __half2 t0 = lxk<3>(vget(A, j));
        __half2 t1 = lxk<3>(vget(A, i));
        vset(A, i, t0); vset(A, j, t1);
      }

    // Ry q0 (lane^2): out = c*mine + (b0? s : -s)*partner
    {
      float sv, cv; __sincosf(0.5f * wD[7 * d], &sv, &cv);
      __half2 c2v = __floats2half2_rn(cv, cv);
      __half2 se2 = __floats2half2_rn(b0 ? sv : -sv, b0 ? sv : -sv);
#pragma unroll
      for (int i = 0; i < 32; ++i) {
        __half2 q = lxk<2>(vget(A, i));
        vset(A, i, __hfma2(c2v, vget(A, i), __hmul2(se2, q)));
      }
    }
    // Ry q1 (lane^1)
    {
      float sv, cv; __sincosf(0.5f * wD[7 * d + 1], &sv, &cv);
      __half2 c2v = __floats2half2_rn(cv, cv);
      __half2 se2 = __floats2half2_rn(b1 ? sv : -sv, b1 ? sv : -sv);
#pragma unroll
      for (int i = 0; i < 32; ++i) {
        __half2 q = lxk<1>(vget(A, i));
        vset(A, i, __hfma2(c2v, vget(A, i), __hmul2(se2, q)));
      }
    }
    // Ry q2..q6 local
    ry_rec<5, 0>(A, [&](int W, __half2& c2, __half2& s2, __half2& ns2) {
      float sv, cv; __sincosf(0.5f * wD[7 * d + W + 2], &sv, &cv);
      c2 = __floats2half2_rn(cv, cv);
      s2 = __floats2half2_rn(sv, sv);
      ns2 = __floats2half2_rn(-sv, -sv);
    });

    // P2 (l->t): flip q4..q6 (local ^7) iff parity(q0..q3) =
    // parc(sub) ^ parc(i&0x18)  (lane-local swap)
    {
      const bool ps = b0 ^ b1;
#pragma unroll
      for (int i = 0; i < 32; ++i)
        if (!(i & 4)) {          // rep of pair {i, i^7}
          const int j = i ^ 7;
          const bool cond = parc(i & 0x18) ? !ps : ps;
          __half2 lo = vget(A, i), hi = vget(A, j);
          vset(A, i, cond ? hi : lo);
          vset(A, j, cond ? lo : hi);
        }
    }
  }

  // readout: class c = q4q5q6 = i&7 (local); quad-sum cross-lane
  float cls[8];
#pragma unroll
  for (int c = 0; c < 8; ++c) cls[c] = 0.f;
#pragma unroll
  for (int i = 0; i < 32; ++i) cls[i & 7] = ampsq(vget(A, i), cls[i & 7]);
  float z4 = 0.f, z5 = 0.f, z6 = 0.f;
#pragma unroll
  for (int c = 0; c < 8; ++c) {
    z4 += (c & 4) ? -cls[c] : cls[c];
    z5 += (c & 2) ? -cls[c] : cls[c];
    z6 += (c & 1) ? -cls[c] : cls[c];
  }
  z4 += lxkf<1>(z4); z5 += lxkf<1>(z5); z6 += lxkf<1>(z6);
  z4 += lxkf<2>(z4); z5 += lxkf<2>(z5); z6 += lxkf<2>(z6);
  if (sub == 0) {
    out_row[6] = z4; out_row[7] = z5; out_row[8] = z6;
  }
}

// ---------------- single fused-dispatch kernel ------------------------------

__global__ void __launch_bounds__(256, 6)
k_all(const float* __restrict__ x,
      const float* __restrict__ wA, const float* __restrict__ wB,
      const float* __restrict__ wC, const float* __restrict__ wD,
      float* __restrict__ out, int B, int gx) {
  const int bx = blockIdx.x;
  if (bx < gx) {
    // ABC role: one thread per element, all three 4q sims
    const int b = bx * 256 + threadIdx.x;
    if (b >= B) return;
    const float* xr = x + (size_t)b * 56;
    float o[6];
    sim4h<0>(xr, wA, &o[0]);
    sim4h<1>(xr, wB, &o[2]);
    sim4h<2>(xr, wC, &o[4]);
    float* op = out + (size_t)b * 9;
#pragma unroll
    for (int i = 0; i < 6; ++i) op[i] = o[i];
  } else {
    // 7q role: 4 lanes per element
    const int t = (bx - gx) * 256 + threadIdx.x;
    const int b = t >> 2;
    if (b >= B) return;
    role7(x + (size_t)b * 56, wD, out + (size_t)b * 9, t & 3);
  }
}

// ---------------- launch ----------------------------------------------------

extern "C" void kernel_launch(void* const* d_in, const int* in_sizes, int n_in,
                              void* d_out, int out_size, void* d_ws, size_t ws_size,
                              hipStream_t stream) {
  const float* x  = (const float*)d_in[0];
  const float* wA = (const float*)d_in[1];
  const float* wB = (const float*)d_in[2];
  const float* wC = (const float*)d_in[3];
  const float* wD = (const float*)d_in[4];
  float* out = (float*)d_out;
  const int B = in_sizes[0] / 56;
  const int threads = 256;

  const int gx = (B + threads - 1) / threads;          // ABC blocks
  const int gy = (4 * B + threads - 1) / threads;      // 7q blocks (4 lanes/elem)
  k_all<<<gx + gy, threads, 0, stream>>>(x, wA, wB, wC, wD, out, B, gx);
}

// Round 12
// 128.728 us; speedup vs baseline: 1.4472x; 1.2197x over previous
//
#include <hip/hip_runtime.h>
#include <hip/hip_fp16.h>

// Batched quantum-circuit sim — return to the BASELINE decomposition (one
// thread = one element, all four sims; lowest total instruction stream of
// any variant tested) hardened with everything proven in R3-R11:
//  - 7q state in TWO vreg64 SSA tuples (R9: only wide-state form proven
//    spill-free), ABC state in vreg16 (R6).
//  - No r[56] bulk preload: scalars loaded at point of use (R4+); x-row
//    stays L1-resident across its ~40 touches. Cuts peak pressure by ~56
//    regs -> 7q phase ~150 live regs < 170 = the 3-waves/SIMD step
//    (baseline with r[56] was >=190 -> 2 waves/SIMD).
//  - ABC sims run and store BEFORE the 7q phase (vreg16 dead when the
//    128-reg state allocates).
//  - One writer per output row (36B contiguous/thread): zero RMW amp.
//  - __launch_bounds__(256,2): loose bounds only — R10/R11 proved ANY
//    tight budget makes the allocator spill the state tuple wholesale.

#define DEVINL __device__ __forceinline__

typedef _Float16 hv2 __attribute__((ext_vector_type(2)));
typedef unsigned int u32;
typedef u32 vreg16 __attribute__((ext_vector_type(16)));
typedef u32 vreg64 __attribute__((ext_vector_type(64)));

struct C2 { __half2 rr, mp; };  // complex const (r,i): rr=(r,r), mp=(-i,+i)

DEVINL C2 mkc(float re, float im) {
  C2 c; c.rr = __floats2half2_rn(re, re); c.mp = __floats2half2_rn(-im, im); return c;
}
DEVINL __half2 mkamp(float re, float im) { return __floats2half2_rn(re, im); }
DEVINL __half2 swap2(__half2 v) { return __lowhigh2highlow(v); }
// (const u) * (amp v):  (r*vr - i*vi, r*vi + i*vr)
DEVINL __half2 cmulc(C2 u, __half2 v) { return __hfma2(u.rr, v, __hmul2(u.mp, swap2(v))); }

DEVINL float ampsq(__half2 v, float acc) {
#if __has_builtin(__builtin_amdgcn_fdot2)
  return __builtin_amdgcn_fdot2(__builtin_bit_cast(hv2, v), __builtin_bit_cast(hv2, v), acc, false);
#else
  float2 f = __half22float2(v);
  return fmaf(f.x, f.x, fmaf(f.y, f.y, acc));
#endif
}

constexpr int parc(int x) { x ^= x >> 4; x ^= x >> 2; x ^= x >> 1; return x & 1; }

struct c32 { float x, y; };
DEVINL c32 cmulf(c32 a, c32 b) { return { a.x*b.x - a.y*b.y, a.x*b.y + a.y*b.x }; }

// ---- SSA state accessors ----------------------------------------------------
template<class VT>
DEVINL __half2 vget(const VT& A, int i) { return __builtin_bit_cast(__half2, (u32)A[i]); }
template<class VT>
DEVINL void vset(VT& A, int i, __half2 v) { A[i] = __builtin_bit_cast(u32, v); }

// 128-amp state = two vreg64 tuples; index folds to constant after unroll.
struct S128 { vreg64 lo, hi; };
DEVINL __half2 vget(const S128& A, int i) {
  u32 u = (i < 64) ? (u32)A.lo[i] : (u32)A.hi[i - 64];
  return __builtin_bit_cast(__half2, u);
}
DEVINL void vset(S128& A, int i, __half2 v) {
  u32 u = __builtin_bit_cast(u32, v);
  if (i < 64) A.lo[i] = u; else A.hi[i - 64] = u;
}

// ---------------- generic gates (qubit W of N; mask = 1<<(N-1-W)) -----------

template<int N, int W, class VT>
DEVINL void g_ry(VT& A, __half2 c2, __half2 s2, __half2 ns2) {
  constexpr int M = 1 << (N - 1 - W);
#pragma unroll
  for (int i = 0; i < (1 << N); ++i) if (!(i & M)) {
    const int j = i | M;
    __half2 v0 = vget(A, i), v1 = vget(A, j);
    vset(A, i, __hfma2(c2, v0, __hmul2(ns2, v1)));
    vset(A, j, __hfma2(c2, v1, __hmul2(s2, v0)));
  }
}

template<int N, int W, class VT>
DEVINL void g_u2(VT& A, C2 u00, C2 u01, C2 u10, C2 u11) {
  constexpr int M = 1 << (N - 1 - W);
#pragma unroll
  for (int i = 0; i < (1 << N); ++i) if (!(i & M)) {
    const int j = i | M;
    __half2 v0 = vget(A, i), v1 = vget(A, j), v0s = swap2(v0), v1s = swap2(v1);
    vset(A, i, __hfma2(u00.rr, v0, __hfma2(u00.mp, v0s, __hfma2(u01.rr, v1, __hmul2(u01.mp, v1s)))));
    vset(A, j, __hfma2(u10.rr, v0, __hfma2(u10.mp, v0s, __hfma2(u11.rr, v1, __hmul2(u11.mp, v1s)))));
  }
}

template<int N, int C, int T, class VT>
DEVINL void g_cnot(VT& A) {
  constexpr int CM = 1 << (N - 1 - C), TM = 1 << (N - 1 - T);
#pragma unroll
  for (int i = 0; i < (1 << N); ++i) if ((i & CM) && !(i & TM)) {
    const int j = i | TM;
    __half2 t = vget(A, i); vset(A, i, vget(A, j)); vset(A, j, t);
  }
}

template<int N, int K, class VT>
DEVINL void chain_cnot(VT& A) {
  if constexpr (K < N - 1) { g_cnot<N, K, K + 1>(A); chain_cnot<N, K + 1>(A); }
}

// ---------------- per-qubit coefficients (f32) ------------------------------
// forward: u = Rz(phi)Ry(pt)Rx(eta)|0>;  reverse merged: U = Rx(phi)Ry(pt)Rz(eta)

DEVINL void mk_u01(float ce, float se, float cp, float sp, float cf, float sf,
                   c32& u0, c32& u1) {
  u0 = cmulf({cf, -sf}, {cp * ce, sp * se});
  u1 = cmulf({cf,  sf}, {sp * ce, -cp * se});
}

DEVINL void mk_U(float ce, float se, float cp, float sp, float cf, float sf,
                 C2& U00, C2& U01, C2& U10, C2& U11) {
  c32 z = {ce, -se}, zb = {ce, se};
  c32 A = cmulf({cf * cp, -sf * sp}, z);
  c32 T = cmulf({cf * sp,  sf * cp}, zb);
  c32 Cc = cmulf({cf * sp, -sf * cp}, z);
  c32 D = cmulf({cf * cp,  sf * sp}, zb);
  U00 = mkc(A.x, A.y); U01 = mkc(-T.x, -T.y); U10 = mkc(Cc.x, Cc.y); U11 = mkc(D.x, D.y);
}

// per-qubit sincos loader (eta_i<0 -> eta=0)
DEVINL void load_sc(const float* __restrict__ xr, int eta_i, int pt_i, int phi_i,
                    float& ce, float& se, float& cp, float& sp, float& cf, float& sf) {
  float e = (eta_i < 0) ? 0.f : xr[eta_i];
  __sincosf(0.5f * e, &se, &ce);
  __sincosf(0.5f * xr[pt_i], &sp, &cp);
  __sincosf(0.5f * xr[phi_i], &sf, &cf);
}

// product state build by doubling (A[0] must be (1,0) on entry).
// step M's qubit lands at bit (N-1-M). CF(M,u0,u1) supplies the column.
template<int N, int M, class VT, class CF>
DEVINL void build_rec(VT& A, CF cf) {
  if constexpr (M < N) {
    c32 u0, u1; cf(M, u0, u1);
    C2 c0 = mkc(u0.x, u0.y), c1 = mkc(u1.x, u1.y);
#pragma unroll
    for (int j = (1 << M) - 1; j >= 0; --j) {
      __half2 s = vget(A, j);
      vset(A, 2 * j,     cmulc(c0, s));
      vset(A, 2 * j + 1, cmulc(c1, s));
    }
    build_rec<N, M + 1>(A, cf);
  }
}

template<int N, int K, class VT, class CF>
DEVINL void usweep_rec(VT& A, CF cf) {
  if constexpr (K < N) {
    C2 U00, U01, U10, U11;
    cf(K, U00, U01, U10, U11);
    g_u2<N, K>(A, U00, U01, U10, U11);
    usweep_rec<N, K + 1>(A, cf);
  }
}

template<int N, int K, class VT, class CF>
DEVINL void ry_rec(VT& A, CF cf) {
  if constexpr (K < N) {
    __half2 c2, s2, ns2;
    cf(K, c2, s2, ns2);
    g_ry<N, K>(A, c2, s2, ns2);
    ry_rec<N, K + 1>(A, cf);
  }
}

// ---------------- 4-qubit block I (verified math, SSA state) ----------------

template<int I>
DEVINL void sim4h(const float* __restrict__ xr, const float* __restrict__ w, float* z) {
  constexpr int PT[3][4]  = {{5, 4, 35, 34}, {3, 33, 31, 2}, {28, 32, 15, 16}};
  constexpr int ETA[3][4] = {{9, 8, 45, 44}, {7, 43, 41, 6}, {38, 42, 19, 20}};
  constexpr int PHI[3][4] = {{13, 12, 55, 54}, {11, 53, 51, 10}, {48, 52, 23, 24}};
  vreg16 A;
  vset(A, 0, mkamp(1.f, 0.f));
  build_rec<4, 0>(A, [&](int M, c32& u0, c32& u1) {
    float ce, se, cp, sp, cf, sf;
    load_sc(xr, ETA[I][M], PT[I][M], PHI[I][M], ce, se, cp, sp, cf, sf);
    mk_u01(ce, se, cp, sp, cf, sf, u0, u1);
  });
  chain_cnot<4, 0>(A);
  usweep_rec<4, 0>(A, [&](int K, C2& U00, C2& U01, C2& U10, C2& U11) {
    float ce, se, cp, sp, cf, sf;
    load_sc(xr, ETA[I][K], PT[I][K], PHI[I][K], ce, se, cp, sp, cf, sf);
    mk_U(ce, se, cp, sp, cf, sf, U00, U01, U10, U11);
  });

  // t->l CNOT block == flip q0,q1 (mask 12) iff parity(b2,b3) (i&3)
#pragma unroll
  for (int i = 0; i < 16; ++i)
    if (parc(i & 3) && !(i & 8)) {
      __half2 t = vget(A, i); vset(A, i, vget(A, i ^ 12)); vset(A, i ^ 12, t);
    }

  ry_rec<4, 0>(A, [&](int K, __half2& c2, __half2& s2, __half2& ns2) {
    float sv, cv; __sincosf(0.5f * w[K], &sv, &cv);
    c2 = __floats2half2_rn(cv, cv);
    s2 = __floats2half2_rn(sv, sv);
    ns2 = __floats2half2_rn(-sv, -sv);
  });

  // l->t CNOT block == flip q2,q3 (mask 3) iff parity(b0,b1) (i&12)
#pragma unroll
  for (int i = 0; i < 16; ++i)
    if (parc(i & 12) && !(i & 2)) {
      __half2 t = vget(A, i); vset(A, i, vget(A, i ^ 3)); vset(A, i ^ 3, t);
    }

  float cls[4];
#pragma unroll
  for (int c = 0; c < 4; ++c) cls[c] = 0.f;
#pragma unroll
  for (int i = 0; i < 16; ++i) cls[i & 3] = ampsq(vget(A, i), cls[i & 3]);
  float z0 = 0.f, z1 = 0.f;
#pragma unroll
  for (int c = 0; c < 4; ++c) {
    z0 += (c & 2) ? -cls[c] : cls[c];
    z1 += (c & 1) ? -cls[c] : cls[c];
  }
  z[0] = z0; z[1] = z1;
}

// ---------------- 7-qubit block (baseline R0 math, S128 SSA state) ----------
// qubit k at bit 6-k. latent=(0..3) trash=(4,5,6) depth=4.

DEVINL void sim7(const float* __restrict__ xr, const float* __restrict__ wD,
                 float* z) {
  constexpr int PT[7]  = {0, 14, 30, 26, 29, 27, 17};
  constexpr int ETA[7] = {-1, 18, 40, 36, 39, 37, 21};  // -1 -> zeros (None)
  constexpr int PHI[7] = {1, 22, 50, 46, 49, 47, 25};

  S128 A;
  vset(A, 0, mkamp(1.f, 0.f));
  build_rec<7, 0>(A, [&](int M, c32& u0, c32& u1) {
    float ce, se, cp, sp, cf, sf;
    load_sc(xr, ETA[M], PT[M], PHI[M], ce, se, cp, sp, cf, sf);
    mk_u01(ce, se, cp, sp, cf, sf, u0, u1);
  });
  chain_cnot<7, 0>(A);
  usweep_rec<7, 0>(A, [&](int K, C2& U00, C2& U01, C2& U10, C2& U11) {
    float ce, se, cp, sp, cf, sf;
    load_sc(xr, ETA[K], PT[K], PHI[K], ce, se, cp, sp, cf, sf);
    mk_U(ce, se, cp, sp, cf, sf, U00, U01, U10, U11);
  });

  // depth loop kept rolled: body stays in L1I
#pragma unroll 1
  for (int d = 0; d < 4; ++d) {
    // t->l block == flip q0..q3 (mask 0x78) iff parity(q4,q5,q6) (i&7)
#pragma unroll
    for (int i = 0; i < 128; ++i)
      if (parc(i & 7) && !(i & 64)) {
        __half2 t = vget(A, i); vset(A, i, vget(A, i ^ 0x78)); vset(A, i ^ 0x78, t);
      }

    ry_rec<7, 0>(A, [&](int K, __half2& c2, __half2& s2, __half2& ns2) {
      float sv, cv; __sincosf(0.5f * wD[7 * d + K], &sv, &cv);
      c2 = __floats2half2_rn(cv, cv);
      s2 = __floats2half2_rn(sv, sv);
      ns2 = __floats2half2_rn(-sv, -sv);
    });

    // l->t block == flip q4..q6 (mask 7) iff parity(q0..q3) (i&0x78)
#pragma unroll
    for (int i = 0; i < 128; ++i)
      if (parc(i & 0x78) && !(i & 4)) {
        __half2 t = vget(A, i); vset(A, i, vget(A, i ^ 7)); vset(A, i ^ 7, t);
      }
  }

  float cls[8];
#pragma unroll
  for (int c = 0; c < 8; ++c) cls[c] = 0.f;
#pragma unroll
  for (int i = 0; i < 128; ++i) cls[i & 7] = ampsq(vget(A, i), cls[i & 7]);
  float z4 = 0.f, z5 = 0.f, z6 = 0.f;
#pragma unroll
  for (int c = 0; c < 8; ++c) {
    z4 += (c & 4) ? -cls[c] : cls[c];
    z5 += (c & 2) ? -cls[c] : cls[c];
    z6 += (c & 1) ? -cls[c] : cls[c];
  }
  z[0] = z4; z[1] = z5; z[2] = z6;
}

// ---------------- fused kernel: one thread per element ----------------------

__global__ void __launch_bounds__(256, 2)
k_all(const float* __restrict__ x,
      const float* __restrict__ wA, const float* __restrict__ wB,
      const float* __restrict__ wC, const float* __restrict__ wD,
      float* __restrict__ out, int B) {
  const int b = blockIdx.x * 256 + threadIdx.x;
  if (b >= B) return;
  const float* xr = x + (size_t)b * 56;

  float o[9];
  // ABC first: vreg16 state is dead before the 128-reg 7q state allocates.
  sim4h<0>(xr, wA, &o[0]);
  sim4h<1>(xr, wB, &o[2]);
  sim4h<2>(xr, wC, &o[4]);
  sim7(xr, wD, &o[6]);

  float* op = out + (size_t)b * 9;
#pragma unroll
  for (int i = 0; i < 9; ++i) op[i] = o[i];
}

// ---------------- launch ----------------------------------------------------

extern "C" void kernel_launch(void* const* d_in, const int* in_sizes, int n_in,
                              void* d_out, int out_size, void* d_ws, size_t ws_size,
                              hipStream_t stream) {
  const float* x  = (const float*)d_in[0];
  const float* wA = (const float*)d_in[1];
  const float* wB = (const float*)d_in[2];
  const float* wC = (const float*)d_in[3];
  const float* wD = (const float*)d_in[4];
  float* out = (float*)d_out;
  const int B = in_sizes[0] / 56;
  const int threads = 256;

  const int blocks = (B + threads - 1) / threads;
  k_all<<<blocks, threads, 0, stream>>>(x, wA, wB, wC, wD, out, B);
}